// Round 7
// baseline (475.907 us; speedup 1.0000x reference)
//
#include <hip/hip_runtime.h>
#include <math.h>

#define NNODES 50000
#define MPAD   50048    // NNODES rounded up to 128
#define D      256
#define K2     512
#define NEDGES 300000
#define NGRAPH 512
#define NLAYERS 3

#define SCB    256
#define NSCB   ((NNODES + SCB - 1) / SCB)   // 196 blocks

typedef __bf16 bf16x8 __attribute__((ext_vector_type(8)));
typedef float  f32x4  __attribute__((ext_vector_type(4)));

__device__ __forceinline__ ushort f2bf(float f) {
    unsigned u = __float_as_uint(f);
    unsigned r = (u + 0x7FFFu + ((u >> 16) & 1u)) >> 16;   // RNE
    return (ushort)r;
}
__device__ __forceinline__ float bf2f(ushort b) {
    return __uint_as_float(((unsigned)b) << 16);
}

__device__ __forceinline__ void stage16(const ushort* g, ushort* l) {
    __builtin_amdgcn_global_load_lds(
        (const __attribute__((address_space(1))) unsigned*)g,
        (__attribute__((address_space(3))) unsigned*)l, 16, 0, 0);
}

// ---------------- CSR build ----------------
__global__ __launch_bounds__(256)
void hist_kernel(const int* __restrict__ dst, int* __restrict__ deg, int nE) {
    int e = blockIdx.x * 256 + threadIdx.x;
    if (e < nE) atomicAdd(&deg[dst[e]], 1);
}

__global__ __launch_bounds__(SCB)
void scan_part_kernel(const int* __restrict__ deg, int* __restrict__ bsum) {
    __shared__ int red[SCB];
    int t = threadIdx.x;
    int i = blockIdx.x * SCB + t;
    red[t] = (i < NNODES) ? deg[i] : 0;
    __syncthreads();
#pragma unroll
    for (int off = SCB / 2; off > 0; off >>= 1) {
        if (t < off) red[t] += red[t + off];
        __syncthreads();
    }
    if (t == 0) bsum[blockIdx.x] = red[0];
}

__global__ __launch_bounds__(256)
void scan_bsum_kernel(const int* __restrict__ bsum, int* __restrict__ boff) {
    __shared__ int p[256];
    int t = threadIdx.x;
    p[t] = (t < NSCB) ? bsum[t] : 0;
    __syncthreads();
    for (int off = 1; off < 256; off <<= 1) {
        int v = (t >= off) ? p[t - off] : 0;
        __syncthreads();
        p[t] += v;
        __syncthreads();
    }
    if (t < NSCB) boff[t] = (t == 0) ? 0 : p[t - 1];
}

__global__ __launch_bounds__(SCB)
void scan_final_kernel(const int* __restrict__ deg, const int* __restrict__ boff,
                       int* __restrict__ row_start, int* __restrict__ cursor) {
    __shared__ int p[SCB];
    int t = threadIdx.x;
    int i = blockIdx.x * SCB + t;
    int v = (i < NNODES) ? deg[i] : 0;
    p[t] = v;
    __syncthreads();
    for (int off = 1; off < SCB; off <<= 1) {
        int u = (t >= off) ? p[t - off] : 0;
        __syncthreads();
        p[t] += u;
        __syncthreads();
    }
    int excl = boff[blockIdx.x] + p[t] - v;
    if (i < NNODES) {
        row_start[i] = excl;
        cursor[i] = excl;
    }
    if (blockIdx.x == 0 && t == 0) row_start[NNODES] = NEDGES;
}

__global__ __launch_bounds__(256)
void fill_kernel(const int* __restrict__ src, const int* __restrict__ dst,
                 int* __restrict__ cursor, int* __restrict__ e_src, int nE) {
    int e = blockIdx.x * 256 + threadIdx.x;
    if (e < nE) {
        int pos = atomicAdd(&cursor[dst[e]], 1);
        e_src[pos] = src[e];
    }
}

// ---------------- graph segment starts (batch sorted) ----------------
__global__ __launch_bounds__(256)
void gstart_kernel(const int* __restrict__ batch, int* __restrict__ gstart) {
    int g = blockIdx.x * 256 + threadIdx.x;
    if (g > NGRAPH) return;
    if (g == NGRAPH) { gstart[g] = NNODES; return; }
    int lo = 0, hi = NNODES;
    while (lo < hi) { int mid = (lo + hi) >> 1; if (batch[mid] < g) lo = mid + 1; else hi = mid; }
    gstart[g] = lo;
}

// ---------------- weight prep: split into hi/lo bf16, [L][n][k] ----------------
__global__ __launch_bounds__(256)
void prep_w_kernel(const float* __restrict__ W_rel, const float* __restrict__ W_root,
                   ushort* __restrict__ Wh, ushort* __restrict__ Wl) {
    int i = blockIdx.x * 256 + threadIdx.x;
    if (i >= NLAYERS * D * K2) return;
    int L = i / (D * K2);
    int rem = i % (D * K2);
    int n = rem / K2;
    int k = rem % K2;
    float v = (k < D) ? W_rel[(size_t)L * D * D + (size_t)k * D + n]
                      : W_root[(size_t)L * D * D + (size_t)(k - D) * D + n];
    ushort hi = f2bf(v);
    float  lo = v - bf2f(hi);
    Wh[i] = hi;
    Wl[i] = f2bf(lo);
}

// ---------------- x f32 -> hi/lo bf16 planes (pad rows zeroed) ----------------
__global__ __launch_bounds__(256)
void cvt_x_kernel(const float* __restrict__ x, ushort* __restrict__ xh,
                  ushort* __restrict__ xl) {
    size_t base = ((size_t)blockIdx.x * 256 + threadIdx.x) * 8;
    if (base >= (size_t)MPAD * D) return;
    ushort h[8], l[8];
    if (base < (size_t)NNODES * D) {
        float4 v0 = *reinterpret_cast<const float4*>(x + base);
        float4 v1 = *reinterpret_cast<const float4*>(x + base + 4);
        float vv[8] = {v0.x, v0.y, v0.z, v0.w, v1.x, v1.y, v1.z, v1.w};
#pragma unroll
        for (int j = 0; j < 8; ++j) {
            h[j] = f2bf(vv[j]);
            l[j] = f2bf(vv[j] - bf2f(h[j]));
        }
    } else {
#pragma unroll
        for (int j = 0; j < 8; ++j) { h[j] = 0; l[j] = 0; }
    }
    *reinterpret_cast<uint4*>(xh + base) = *reinterpret_cast<uint4*>(h);
    *reinterpret_cast<uint4*>(xl + base) = *reinterpret_cast<uint4*>(l);
}

// ---------------- gather-sum over hi/lo planes, writes hi/lo planes ----------------
__global__ __launch_bounds__(256)
void gather_hl_kernel(const ushort* __restrict__ ph, const ushort* __restrict__ pl,
                      const int* __restrict__ row_start, const int* __restrict__ e_src,
                      ushort* __restrict__ gh, ushort* __restrict__ gl) {
    int t = threadIdx.x;
    int n = blockIdx.x * 4 + (t >> 6);
    if (n >= NNODES) return;
    int lane = t & 63;
    int beg = row_start[n], end = row_start[n + 1];
    float a0 = 0.f, a1 = 0.f, a2 = 0.f, a3 = 0.f;
    int j = beg;
    for (; j + 4 <= end; j += 4) {
        int s0 = e_src[j], s1 = e_src[j + 1], s2 = e_src[j + 2], s3 = e_src[j + 3];
        ushort4 h0 = *reinterpret_cast<const ushort4*>(ph + (size_t)s0 * D + lane * 4);
        ushort4 l0 = *reinterpret_cast<const ushort4*>(pl + (size_t)s0 * D + lane * 4);
        ushort4 h1 = *reinterpret_cast<const ushort4*>(ph + (size_t)s1 * D + lane * 4);
        ushort4 l1 = *reinterpret_cast<const ushort4*>(pl + (size_t)s1 * D + lane * 4);
        ushort4 h2 = *reinterpret_cast<const ushort4*>(ph + (size_t)s2 * D + lane * 4);
        ushort4 l2 = *reinterpret_cast<const ushort4*>(pl + (size_t)s2 * D + lane * 4);
        ushort4 h3 = *reinterpret_cast<const ushort4*>(ph + (size_t)s3 * D + lane * 4);
        ushort4 l3 = *reinterpret_cast<const ushort4*>(pl + (size_t)s3 * D + lane * 4);
        a0 += (bf2f(h0.x) + bf2f(l0.x)) + (bf2f(h1.x) + bf2f(l1.x)) +
              (bf2f(h2.x) + bf2f(l2.x)) + (bf2f(h3.x) + bf2f(l3.x));
        a1 += (bf2f(h0.y) + bf2f(l0.y)) + (bf2f(h1.y) + bf2f(l1.y)) +
              (bf2f(h2.y) + bf2f(l2.y)) + (bf2f(h3.y) + bf2f(l3.y));
        a2 += (bf2f(h0.z) + bf2f(l0.z)) + (bf2f(h1.z) + bf2f(l1.z)) +
              (bf2f(h2.z) + bf2f(l2.z)) + (bf2f(h3.z) + bf2f(l3.z));
        a3 += (bf2f(h0.w) + bf2f(l0.w)) + (bf2f(h1.w) + bf2f(l1.w)) +
              (bf2f(h2.w) + bf2f(l2.w)) + (bf2f(h3.w) + bf2f(l3.w));
    }
    for (; j < end; ++j) {
        int s = e_src[j];
        ushort4 h = *reinterpret_cast<const ushort4*>(ph + (size_t)s * D + lane * 4);
        ushort4 l = *reinterpret_cast<const ushort4*>(pl + (size_t)s * D + lane * 4);
        a0 += bf2f(h.x) + bf2f(l.x);
        a1 += bf2f(h.y) + bf2f(l.y);
        a2 += bf2f(h.z) + bf2f(l.z);
        a3 += bf2f(h.w) + bf2f(l.w);
    }
    ushort4 oh, ol;
    oh.x = f2bf(a0); ol.x = f2bf(a0 - bf2f(oh.x));
    oh.y = f2bf(a1); ol.y = f2bf(a1 - bf2f(oh.y));
    oh.z = f2bf(a2); ol.z = f2bf(a2 - bf2f(oh.z));
    oh.w = f2bf(a3); ol.w = f2bf(a3 - bf2f(oh.w));
    *reinterpret_cast<ushort4*>(gh + (size_t)n * D + lane * 4) = oh;
    *reinterpret_cast<ushort4*>(gl + (size_t)n * D + lane * 4) = ol;
}

// ---------------- split-bf16 MFMA GEMM, all operands staged via global_load_lds ----------------
// out = relu([G|X] @ W^T + bias); G,X,W given as hi/lo bf16 plane pairs; out written as hi/lo planes
#define GBM 128
#define GBN 128
#define GBK 32

__global__ __launch_bounds__(256)
void gemm_hl_kernel(const ushort* __restrict__ Gh, const ushort* __restrict__ Gl,
                    const ushort* __restrict__ Xh, const ushort* __restrict__ Xl,
                    const ushort* __restrict__ Wh, const ushort* __restrict__ Wl,
                    const float* __restrict__ bias,
                    ushort* __restrict__ outh, ushort* __restrict__ outl) {
    __shared__ ushort AhS[GBM * GBK];   // 8 KB each, row r at elem r*32 (64B), swizzled chunks
    __shared__ ushort AlS[GBM * GBK];
    __shared__ ushort BhS[GBN * GBK];
    __shared__ ushort BlS[GBN * GBK];

    int t = threadIdx.x;
    int wid = t >> 6, lane = t & 63;
    int m0 = blockIdx.x * GBM;
    int n0 = blockIdx.y * GBN;
    int wr = wid >> 1, wc = wid & 1;

    f32x4 acc[4][4];
#pragma unroll
    for (int m = 0; m < 4; ++m)
#pragma unroll
        for (int n = 0; n < 4; ++n)
            acc[m][n] = (f32x4){0.f, 0.f, 0.f, 0.f};

    for (int k0 = 0; k0 < K2; k0 += GBK) {
        const ushort* ah = (k0 < D) ? Gh : Xh;
        const ushort* al = (k0 < D) ? Gl : Xl;
        int kk = k0 & (D - 1);

        // stage 4 planes; pre-swizzled global source: phys chunk sub holds kh=((row>>1)&3)^sub
#pragma unroll
        for (int op = 0; op < 2; ++op) {
            int idx = op * 256 + wid * 64 + lane;
            int row = idx >> 2, sub = idx & 3;
            int kh = ((row >> 1) & 3) ^ sub;
            size_t ldso = (size_t)(op * 256 + wid * 64) * 8;
            stage16(ah + (size_t)(m0 + row) * D + kk + kh * 8, AhS + ldso);
            stage16(al + (size_t)(m0 + row) * D + kk + kh * 8, AlS + ldso);
            stage16(Wh + (size_t)(n0 + row) * K2 + k0 + kh * 8, BhS + ldso);
            stage16(Wl + (size_t)(n0 + row) * K2 + k0 + kh * 8, BlS + ldso);
        }
        __syncthreads();   // drains vmcnt before LDS reads

        bf16x8 fah[4], fal[4], fbh[4], fbl[4];
        int half = lane >> 4;
#pragma unroll
        for (int m = 0; m < 4; ++m) {
            int row = wr * 64 + m * 16 + (lane & 15);
            int off = row * GBK + ((((row >> 1) & 3) ^ half) * 8);
            fah[m] = *reinterpret_cast<const bf16x8*>(&AhS[off]);
            fal[m] = *reinterpret_cast<const bf16x8*>(&AlS[off]);
        }
#pragma unroll
        for (int n = 0; n < 4; ++n) {
            int row = wc * 64 + n * 16 + (lane & 15);
            int off = row * GBK + ((((row >> 1) & 3) ^ half) * 8);
            fbh[n] = *reinterpret_cast<const bf16x8*>(&BhS[off]);
            fbl[n] = *reinterpret_cast<const bf16x8*>(&BlS[off]);
        }
#pragma unroll
        for (int m = 0; m < 4; ++m)
#pragma unroll
            for (int n = 0; n < 4; ++n) {
                acc[m][n] = __builtin_amdgcn_mfma_f32_16x16x32_bf16(fah[m], fbh[n], acc[m][n], 0, 0, 0);
                acc[m][n] = __builtin_amdgcn_mfma_f32_16x16x32_bf16(fah[m], fbl[n], acc[m][n], 0, 0, 0);
                acc[m][n] = __builtin_amdgcn_mfma_f32_16x16x32_bf16(fal[m], fbh[n], acc[m][n], 0, 0, 0);
            }
        __syncthreads();
    }

    // epilogue: bias + relu -> hi/lo bf16 planes
    int half = lane >> 4;
#pragma unroll
    for (int n = 0; n < 4; ++n) {
        int col = n0 + wc * 64 + n * 16 + (lane & 15);
        float bv = bias[col];
#pragma unroll
        for (int m = 0; m < 4; ++m) {
            int rbase = m0 + wr * 64 + m * 16 + half * 4;
#pragma unroll
            for (int j = 0; j < 4; ++j) {
                int r = rbase + j;
                if (r < NNODES) {
                    float v = fmaxf(acc[m][n][j] + bv, 0.f);
                    ushort hv = f2bf(v);
                    outh[(size_t)r * D + col] = hv;
                    outl[(size_t)r * D + col] = f2bf(v - bf2f(hv));
                }
            }
        }
    }
}

// ---------------- segmented pool over hi/lo planes (f32 out) ----------------
__global__ __launch_bounds__(256)
void pool_seg_kernel(const ushort* __restrict__ ph, const ushort* __restrict__ pl,
                     const int* __restrict__ gstart, float* __restrict__ pooled) {
    __shared__ float red[4][D];
    int g = blockIdx.x;
    int t = threadIdx.x, wid = t >> 6, lane = t & 63;
    int beg = gstart[g], end = gstart[g + 1];
    float a0 = 0.f, a1 = 0.f, a2 = 0.f, a3 = 0.f;
    for (int r = beg + wid; r < end; r += 4) {
        ushort4 h = *reinterpret_cast<const ushort4*>(ph + (size_t)r * D + lane * 4);
        ushort4 l = *reinterpret_cast<const ushort4*>(pl + (size_t)r * D + lane * 4);
        a0 += bf2f(h.x) + bf2f(l.x);
        a1 += bf2f(h.y) + bf2f(l.y);
        a2 += bf2f(h.z) + bf2f(l.z);
        a3 += bf2f(h.w) + bf2f(l.w);
    }
    red[wid][lane * 4 + 0] = a0;
    red[wid][lane * 4 + 1] = a1;
    red[wid][lane * 4 + 2] = a2;
    red[wid][lane * 4 + 3] = a3;
    __syncthreads();
    float s = red[0][t] + red[1][t] + red[2][t] + red[3][t];
    pooled[(size_t)g * D + t] = s;
}

// ---------------- MLP layer 1 (f32) ----------------
__global__ __launch_bounds__(256)
void mlp1_kernel(const float* __restrict__ pooled, const float* __restrict__ W1,
                 const float* __restrict__ b1, float* __restrict__ h) {
    __shared__ float p[D];
    int g = blockIdx.x, t = threadIdx.x;
    p[t] = pooled[(size_t)g * D + t];
    __syncthreads();
    float4 acc = make_float4(0.f, 0.f, 0.f, 0.f);
    for (int k = 0; k < D; ++k) {
        float4 w = *reinterpret_cast<const float4*>(W1 + (size_t)k * 1024 + t * 4);
        float pv = p[k];
        acc.x += pv * w.x; acc.y += pv * w.y; acc.z += pv * w.z; acc.w += pv * w.w;
    }
    float4 b = *reinterpret_cast<const float4*>(b1 + t * 4);
    acc.x = fmaxf(acc.x + b.x, 0.f);
    acc.y = fmaxf(acc.y + b.y, 0.f);
    acc.z = fmaxf(acc.z + b.z, 0.f);
    acc.w = fmaxf(acc.w + b.w, 0.f);
    *reinterpret_cast<float4*>(h + (size_t)g * 1024 + t * 4) = acc;
}

// ---------------- MLP layer 2 (f32) ----------------
__global__ __launch_bounds__(256)
void mlp2_kernel(const float* __restrict__ h, const float* __restrict__ W2,
                 const float* __restrict__ b2, float* __restrict__ out) {
    __shared__ float red[8][32];
    int g = blockIdx.x, t = threadIdx.x;
    int c = t & 31, kc = t >> 5;
    float s = 0.f;
    const float* hr = h + (size_t)g * 1024;
    for (int k = kc * 128; k < kc * 128 + 128; ++k)
        s += hr[k] * W2[(size_t)k * 32 + c];
    red[kc][c] = s;
    __syncthreads();
    if (t < 32) {
        float v = b2[t];
#pragma unroll
        for (int i = 0; i < 8; ++i) v += red[i][t];
        out[(size_t)g * 32 + t] = 1.f / (1.f + expf(-v));
    }
}

extern "C" void kernel_launch(void* const* d_in, const int* in_sizes, int n_in,
                              void* d_out, int out_size, void* d_ws, size_t ws_size,
                              hipStream_t stream) {
    const float* x      = (const float*)d_in[0];
    const int*   ei     = (const int*)d_in[1];
    const int*   batch  = (const int*)d_in[2];
    const float* W_rel  = (const float*)d_in[3];
    const float* W_root = (const float*)d_in[4];
    const float* b_conv = (const float*)d_in[5];
    const float* W1     = (const float*)d_in[6];
    const float* b1     = (const float*)d_in[7];
    const float* W2     = (const float*)d_in[8];
    const float* b2     = (const float*)d_in[9];
    float* outp = (float*)d_out;

    const size_t NF = (size_t)MPAD * D;
    // activation plane pairs: P0 (xh/xl), P1 (yh/yl), G (gh/gl)
    ushort* xh = (ushort*)d_ws;
    ushort* xl = xh + NF;
    ushort* yh = xl + NF;
    ushort* yl = yh + NF;
    ushort* gh = yl + NF;
    ushort* gl = gh + NF;
    ushort* Wh = gl + NF;                    // 3*256*512 each
    ushort* Wl = Wh + (size_t)NLAYERS * D * K2;
    float* pooled = (float*)(Wl + (size_t)NLAYERS * D * K2);
    float* hbuf   = pooled + (size_t)NGRAPH * D;
    int* deg       = (int*)(hbuf + (size_t)NGRAPH * 1024);
    int* row_start = deg + NNODES;           // NNODES+1
    int* cursor    = row_start + NNODES + 1;
    int* e_src     = cursor + NNODES;        // NEDGES
    int* gstart    = e_src + NEDGES;         // NGRAPH+1
    int* bsum      = gstart + NGRAPH + 1;    // NSCB
    int* boff      = bsum + NSCB;            // NSCB

    const int* srcp = ei;
    const int* dstp = ei + NEDGES;

    // CSR build (reused by all layers)
    hipMemsetAsync(deg, 0, NNODES * sizeof(int), stream);
    hist_kernel<<<(NEDGES + 255) / 256, 256, 0, stream>>>(dstp, deg, NEDGES);
    scan_part_kernel<<<NSCB, SCB, 0, stream>>>(deg, bsum);
    scan_bsum_kernel<<<1, 256, 0, stream>>>(bsum, boff);
    scan_final_kernel<<<NSCB, SCB, 0, stream>>>(deg, boff, row_start, cursor);
    fill_kernel<<<(NEDGES + 255) / 256, 256, 0, stream>>>(srcp, dstp, cursor, e_src, NEDGES);
    gstart_kernel<<<3, 256, 0, stream>>>(batch, gstart);

    prep_w_kernel<<<(NLAYERS * D * K2 + 255) / 256, 256, 0, stream>>>(W_rel, W_root, Wh, Wl);
    cvt_x_kernel<<<(int)((NF / 8 + 255) / 256), 256, 0, stream>>>(x, xh, xl);

    int gatherBlocks = (NNODES + 3) / 4;
    dim3 ggrid(MPAD / GBM, D / GBN);

    const ushort* curh = xh; const ushort* curl = xl;
    ushort* nxth = yh;       ushort* nxtl = yl;
    for (int L = 0; L < NLAYERS; ++L) {
        gather_hl_kernel<<<gatherBlocks, 256, 0, stream>>>(curh, curl, row_start, e_src, gh, gl);
        gemm_hl_kernel<<<ggrid, 256, 0, stream>>>(gh, gl, curh, curl,
                                                  Wh + (size_t)L * D * K2,
                                                  Wl + (size_t)L * D * K2,
                                                  b_conv + (size_t)L * D,
                                                  nxth, nxtl);
        // swap P-pair roles
        const ushort* th = curh; const ushort* tl = curl;
        curh = nxth; curl = nxtl;
        nxth = (ushort*)th; nxtl = (ushort*)tl;
        if (L == 0) { nxth = xh; nxtl = xl; }   // after L0: cur=P1, next writes into P0
    }

    pool_seg_kernel<<<NGRAPH, 256, 0, stream>>>(curh, curl, gstart, pooled);
    mlp1_kernel<<<NGRAPH, 256, 0, stream>>>(pooled, W1, b1, hbuf);
    mlp2_kernel<<<NGRAPH, 256, 0, stream>>>(hbuf, W2, b2, outp);
}

// Round 8
// 465.242 us; speedup vs baseline: 1.0229x; 1.0229x over previous
//
#include <hip/hip_runtime.h>
#include <math.h>

#define NNODES 50000
#define MPAD   50048    // NNODES rounded up to 128
#define D      256
#define K2     512
#define NEDGES 300000
#define NGRAPH 512
#define NLAYERS 3

#define SCB    256
#define NSCB   ((NNODES + SCB - 1) / SCB)   // 196 blocks

typedef __bf16 bf16x8 __attribute__((ext_vector_type(8)));
typedef float  f32x4  __attribute__((ext_vector_type(4)));

__device__ __forceinline__ ushort f2bf(float f) {
    unsigned u = __float_as_uint(f);
    unsigned r = (u + 0x7FFFu + ((u >> 16) & 1u)) >> 16;   // RNE
    return (ushort)r;
}
__device__ __forceinline__ float bf2f(ushort b) {
    return __uint_as_float(((unsigned)b) << 16);
}

__device__ __forceinline__ void stage16(const ushort* g, ushort* l) {
    __builtin_amdgcn_global_load_lds(
        (const __attribute__((address_space(1))) unsigned*)g,
        (__attribute__((address_space(3))) unsigned*)l, 16, 0, 0);
}

// ---------------- CSR build ----------------
__global__ __launch_bounds__(256)
void hist_kernel(const int* __restrict__ dst, int* __restrict__ deg, int nE) {
    int e = blockIdx.x * 256 + threadIdx.x;
    if (e < nE) atomicAdd(&deg[dst[e]], 1);
}

__global__ __launch_bounds__(SCB)
void scan_part_kernel(const int* __restrict__ deg, int* __restrict__ bsum) {
    __shared__ int red[SCB];
    int t = threadIdx.x;
    int i = blockIdx.x * SCB + t;
    red[t] = (i < NNODES) ? deg[i] : 0;
    __syncthreads();
#pragma unroll
    for (int off = SCB / 2; off > 0; off >>= 1) {
        if (t < off) red[t] += red[t + off];
        __syncthreads();
    }
    if (t == 0) bsum[blockIdx.x] = red[0];
}

__global__ __launch_bounds__(256)
void scan_bsum_kernel(const int* __restrict__ bsum, int* __restrict__ boff) {
    __shared__ int p[256];
    int t = threadIdx.x;
    p[t] = (t < NSCB) ? bsum[t] : 0;
    __syncthreads();
    for (int off = 1; off < 256; off <<= 1) {
        int v = (t >= off) ? p[t - off] : 0;
        __syncthreads();
        p[t] += v;
        __syncthreads();
    }
    if (t < NSCB) boff[t] = (t == 0) ? 0 : p[t - 1];
}

__global__ __launch_bounds__(SCB)
void scan_final_kernel(const int* __restrict__ deg, const int* __restrict__ boff,
                       int* __restrict__ row_start, int* __restrict__ cursor) {
    __shared__ int p[SCB];
    int t = threadIdx.x;
    int i = blockIdx.x * SCB + t;
    int v = (i < NNODES) ? deg[i] : 0;
    p[t] = v;
    __syncthreads();
    for (int off = 1; off < SCB; off <<= 1) {
        int u = (t >= off) ? p[t - off] : 0;
        __syncthreads();
        p[t] += u;
        __syncthreads();
    }
    int excl = boff[blockIdx.x] + p[t] - v;
    if (i < NNODES) {
        row_start[i] = excl;
        cursor[i] = excl;
    }
    if (blockIdx.x == 0 && t == 0) row_start[NNODES] = NEDGES;
}

__global__ __launch_bounds__(256)
void fill_kernel(const int* __restrict__ src, const int* __restrict__ dst,
                 int* __restrict__ cursor, int* __restrict__ e_src, int nE) {
    int e = blockIdx.x * 256 + threadIdx.x;
    if (e < nE) {
        int pos = atomicAdd(&cursor[dst[e]], 1);
        e_src[pos] = src[e];
    }
}

// ---------------- graph segment starts (batch sorted) ----------------
__global__ __launch_bounds__(256)
void gstart_kernel(const int* __restrict__ batch, int* __restrict__ gstart) {
    int g = blockIdx.x * 256 + threadIdx.x;
    if (g > NGRAPH) return;
    if (g == NGRAPH) { gstart[g] = NNODES; return; }
    int lo = 0, hi = NNODES;
    while (lo < hi) { int mid = (lo + hi) >> 1; if (batch[mid] < g) lo = mid + 1; else hi = mid; }
    gstart[g] = lo;
}

// ---------------- weight prep: split into hi/lo bf16, [L][n][k] ----------------
__global__ __launch_bounds__(256)
void prep_w_kernel(const float* __restrict__ W_rel, const float* __restrict__ W_root,
                   ushort* __restrict__ Wh, ushort* __restrict__ Wl) {
    int i = blockIdx.x * 256 + threadIdx.x;
    if (i >= NLAYERS * D * K2) return;
    int L = i / (D * K2);
    int rem = i % (D * K2);
    int n = rem / K2;
    int k = rem % K2;
    float v = (k < D) ? W_rel[(size_t)L * D * D + (size_t)k * D + n]
                      : W_root[(size_t)L * D * D + (size_t)(k - D) * D + n];
    ushort hi = f2bf(v);
    float  lo = v - bf2f(hi);
    Wh[i] = hi;
    Wl[i] = f2bf(lo);
}

// ---------------- x f32 -> hi/lo bf16 planes (pad rows zeroed) ----------------
__global__ __launch_bounds__(256)
void cvt_x_kernel(const float* __restrict__ x, ushort* __restrict__ xh,
                  ushort* __restrict__ xl) {
    size_t base = ((size_t)blockIdx.x * 256 + threadIdx.x) * 8;
    if (base >= (size_t)MPAD * D) return;
    ushort h[8], l[8];
    if (base < (size_t)NNODES * D) {
        float4 v0 = *reinterpret_cast<const float4*>(x + base);
        float4 v1 = *reinterpret_cast<const float4*>(x + base + 4);
        float vv[8] = {v0.x, v0.y, v0.z, v0.w, v1.x, v1.y, v1.z, v1.w};
#pragma unroll
        for (int j = 0; j < 8; ++j) {
            h[j] = f2bf(vv[j]);
            l[j] = f2bf(vv[j] - bf2f(h[j]));
        }
    } else {
#pragma unroll
        for (int j = 0; j < 8; ++j) { h[j] = 0; l[j] = 0; }
    }
    *reinterpret_cast<uint4*>(xh + base) = *reinterpret_cast<uint4*>(h);
    *reinterpret_cast<uint4*>(xl + base) = *reinterpret_cast<uint4*>(l);
}

// ---------------- gather-sum over hi/lo planes, writes hi/lo planes ----------------
__global__ __launch_bounds__(256)
void gather_hl_kernel(const ushort* __restrict__ ph, const ushort* __restrict__ pl,
                      const int* __restrict__ row_start, const int* __restrict__ e_src,
                      ushort* __restrict__ gh, ushort* __restrict__ gl) {
    int t = threadIdx.x;
    int n = blockIdx.x * 4 + (t >> 6);
    if (n >= NNODES) return;
    int lane = t & 63;
    int beg = row_start[n], end = row_start[n + 1];
    float a0 = 0.f, a1 = 0.f, a2 = 0.f, a3 = 0.f;
    int j = beg;
    for (; j + 4 <= end; j += 4) {
        int s0 = e_src[j], s1 = e_src[j + 1], s2 = e_src[j + 2], s3 = e_src[j + 3];
        ushort4 h0 = *reinterpret_cast<const ushort4*>(ph + (size_t)s0 * D + lane * 4);
        ushort4 l0 = *reinterpret_cast<const ushort4*>(pl + (size_t)s0 * D + lane * 4);
        ushort4 h1 = *reinterpret_cast<const ushort4*>(ph + (size_t)s1 * D + lane * 4);
        ushort4 l1 = *reinterpret_cast<const ushort4*>(pl + (size_t)s1 * D + lane * 4);
        ushort4 h2 = *reinterpret_cast<const ushort4*>(ph + (size_t)s2 * D + lane * 4);
        ushort4 l2 = *reinterpret_cast<const ushort4*>(pl + (size_t)s2 * D + lane * 4);
        ushort4 h3 = *reinterpret_cast<const ushort4*>(ph + (size_t)s3 * D + lane * 4);
        ushort4 l3 = *reinterpret_cast<const ushort4*>(pl + (size_t)s3 * D + lane * 4);
        a0 += (bf2f(h0.x) + bf2f(l0.x)) + (bf2f(h1.x) + bf2f(l1.x)) +
              (bf2f(h2.x) + bf2f(l2.x)) + (bf2f(h3.x) + bf2f(l3.x));
        a1 += (bf2f(h0.y) + bf2f(l0.y)) + (bf2f(h1.y) + bf2f(l1.y)) +
              (bf2f(h2.y) + bf2f(l2.y)) + (bf2f(h3.y) + bf2f(l3.y));
        a2 += (bf2f(h0.z) + bf2f(l0.z)) + (bf2f(h1.z) + bf2f(l1.z)) +
              (bf2f(h2.z) + bf2f(l2.z)) + (bf2f(h3.z) + bf2f(l3.z));
        a3 += (bf2f(h0.w) + bf2f(l0.w)) + (bf2f(h1.w) + bf2f(l1.w)) +
              (bf2f(h2.w) + bf2f(l2.w)) + (bf2f(h3.w) + bf2f(l3.w));
    }
    for (; j < end; ++j) {
        int s = e_src[j];
        ushort4 h = *reinterpret_cast<const ushort4*>(ph + (size_t)s * D + lane * 4);
        ushort4 l = *reinterpret_cast<const ushort4*>(pl + (size_t)s * D + lane * 4);
        a0 += bf2f(h.x) + bf2f(l.x);
        a1 += bf2f(h.y) + bf2f(l.y);
        a2 += bf2f(h.z) + bf2f(l.z);
        a3 += bf2f(h.w) + bf2f(l.w);
    }
    ushort4 oh, ol;
    oh.x = f2bf(a0); ol.x = f2bf(a0 - bf2f(oh.x));
    oh.y = f2bf(a1); ol.y = f2bf(a1 - bf2f(oh.y));
    oh.z = f2bf(a2); ol.z = f2bf(a2 - bf2f(oh.z));
    oh.w = f2bf(a3); ol.w = f2bf(a3 - bf2f(oh.w));
    *reinterpret_cast<ushort4*>(gh + (size_t)n * D + lane * 4) = oh;
    *reinterpret_cast<ushort4*>(gl + (size_t)n * D + lane * 4) = ol;
}

// ---------------- split-bf16 MFMA GEMM, double-buffered 2-phase pipeline ----------------
// out = relu([G|X] @ W^T + bias); all operands hi/lo bf16 plane pairs
#define GBM 128
#define GBN 128
#define GBK 32
#define NKS (K2 / GBK)   // 16

__global__ __launch_bounds__(256)
void gemm_hl_kernel(const ushort* __restrict__ Gh, const ushort* __restrict__ Gl,
                    const ushort* __restrict__ Xh, const ushort* __restrict__ Xl,
                    const ushort* __restrict__ Wh, const ushort* __restrict__ Wl,
                    const float* __restrict__ bias,
                    ushort* __restrict__ outh, ushort* __restrict__ outl) {
    // 2 buffers x 4 planes (Ah,Al,Bh,Bl) x 8KB = 64 KB
    __shared__ ushort S[2][4][GBM * GBK];

    int t = threadIdx.x;
    int wid = t >> 6, lane = t & 63;
    int m0 = blockIdx.x * GBM;
    int n0 = blockIdx.y * GBN;
    int wr = wid >> 1, wc = wid & 1;

    f32x4 acc[4][4];
#pragma unroll
    for (int m = 0; m < 4; ++m)
#pragma unroll
        for (int n = 0; n < 4; ++n)
            acc[m][n] = (f32x4){0.f, 0.f, 0.f, 0.f};

    // staging lane geometry (constant across K-steps)
    // op in {0,1}: idx = op*256 + wid*64 + lane; row = idx>>2, sub = idx&3
    // pre-swizzled source: physical chunk sub holds k-half ((row>>1)&3)^sub
    int idx0 = wid * 64 + lane;
    int row0 = idx0 >> 2, sub0 = idx0 & 3;
    int kh0 = ((row0 >> 1) & 3) ^ sub0;
    int idx1 = 256 + idx0;
    int row1 = idx1 >> 2, sub1 = idx1 & 3;
    int kh1 = ((row1 >> 1) & 3) ^ sub1;
    size_t ldso0 = (size_t)(wid * 64) * 8;
    size_t ldso1 = (size_t)(256 + wid * 64) * 8;

    // prologue: stage K-step 0 into buffer 0
    {
        stage16(Gh + (size_t)(m0 + row0) * D + kh0 * 8, &S[0][0][ldso0]);
        stage16(Gh + (size_t)(m0 + row1) * D + kh1 * 8, &S[0][0][ldso1]);
        stage16(Gl + (size_t)(m0 + row0) * D + kh0 * 8, &S[0][1][ldso0]);
        stage16(Gl + (size_t)(m0 + row1) * D + kh1 * 8, &S[0][1][ldso1]);
        stage16(Wh + (size_t)(n0 + row0) * K2 + kh0 * 8, &S[0][2][ldso0]);
        stage16(Wh + (size_t)(n0 + row1) * K2 + kh1 * 8, &S[0][2][ldso1]);
        stage16(Wl + (size_t)(n0 + row0) * K2 + kh0 * 8, &S[0][3][ldso0]);
        stage16(Wl + (size_t)(n0 + row1) * K2 + kh1 * 8, &S[0][3][ldso1]);
    }
    __syncthreads();

    int cur = 0;
    for (int ks = 0; ks < NKS; ++ks) {
        // ---- issue next K-step's stages into the other buffer (overlaps compute below)
        if (ks + 1 < NKS) {
            int k0 = (ks + 1) * GBK;
            const ushort* ah = (k0 < D) ? Gh : Xh;
            const ushort* al = (k0 < D) ? Gl : Xl;
            int kk = k0 & (D - 1);
            int nb = cur ^ 1;
            stage16(ah + (size_t)(m0 + row0) * D + kk + kh0 * 8, &S[nb][0][ldso0]);
            stage16(ah + (size_t)(m0 + row1) * D + kk + kh1 * 8, &S[nb][0][ldso1]);
            stage16(al + (size_t)(m0 + row0) * D + kk + kh0 * 8, &S[nb][1][ldso0]);
            stage16(al + (size_t)(m0 + row1) * D + kk + kh1 * 8, &S[nb][1][ldso1]);
            stage16(Wh + (size_t)(n0 + row0) * K2 + k0 + kh0 * 8, &S[nb][2][ldso0]);
            stage16(Wh + (size_t)(n0 + row1) * K2 + k0 + kh1 * 8, &S[nb][2][ldso1]);
            stage16(Wl + (size_t)(n0 + row0) * K2 + k0 + kh0 * 8, &S[nb][3][ldso0]);
            stage16(Wl + (size_t)(n0 + row1) * K2 + k0 + kh1 * 8, &S[nb][3][ldso1]);
        }

        // ---- compute current buffer
        bf16x8 fah[4], fal[4], fbh[4], fbl[4];
        int half = lane >> 4;
#pragma unroll
        for (int m = 0; m < 4; ++m) {
            int row = wr * 64 + m * 16 + (lane & 15);
            int off = row * GBK + ((((row >> 1) & 3) ^ half) * 8);
            fah[m] = *reinterpret_cast<const bf16x8*>(&S[cur][0][off]);
            fal[m] = *reinterpret_cast<const bf16x8*>(&S[cur][1][off]);
        }
#pragma unroll
        for (int n = 0; n < 4; ++n) {
            int row = wc * 64 + n * 16 + (lane & 15);
            int off = row * GBK + ((((row >> 1) & 3) ^ half) * 8);
            fbh[n] = *reinterpret_cast<const bf16x8*>(&S[cur][2][off]);
            fbl[n] = *reinterpret_cast<const bf16x8*>(&S[cur][3][off]);
        }
#pragma unroll
        for (int m = 0; m < 4; ++m)
#pragma unroll
            for (int n = 0; n < 4; ++n) {
                acc[m][n] = __builtin_amdgcn_mfma_f32_16x16x32_bf16(fah[m], fbh[n], acc[m][n], 0, 0, 0);
                acc[m][n] = __builtin_amdgcn_mfma_f32_16x16x32_bf16(fah[m], fbl[n], acc[m][n], 0, 0, 0);
                acc[m][n] = __builtin_amdgcn_mfma_f32_16x16x32_bf16(fal[m], fbh[n], acc[m][n], 0, 0, 0);
            }

        // one barrier per K-step: drains next-buffer stages (vmcnt) and
        // guarantees all waves finished reading S[cur] before it is overwritten
        __syncthreads();
        cur ^= 1;
    }

    // epilogue: bias + relu -> hi/lo bf16 planes
    int half = lane >> 4;
#pragma unroll
    for (int n = 0; n < 4; ++n) {
        int col = n0 + wc * 64 + n * 16 + (lane & 15);
        float bv = bias[col];
#pragma unroll
        for (int m = 0; m < 4; ++m) {
            int rbase = m0 + wr * 64 + m * 16 + half * 4;
#pragma unroll
            for (int j = 0; j < 4; ++j) {
                int r = rbase + j;
                if (r < NNODES) {
                    float v = fmaxf(acc[m][n][j] + bv, 0.f);
                    ushort hv = f2bf(v);
                    outh[(size_t)r * D + col] = hv;
                    outl[(size_t)r * D + col] = f2bf(v - bf2f(hv));
                }
            }
        }
    }
}

// ---------------- segmented pool over hi/lo planes (f32 out) ----------------
__global__ __launch_bounds__(256)
void pool_seg_kernel(const ushort* __restrict__ ph, const ushort* __restrict__ pl,
                     const int* __restrict__ gstart, float* __restrict__ pooled) {
    __shared__ float red[4][D];
    int g = blockIdx.x;
    int t = threadIdx.x, wid = t >> 6, lane = t & 63;
    int beg = gstart[g], end = gstart[g + 1];
    float a0 = 0.f, a1 = 0.f, a2 = 0.f, a3 = 0.f;
    for (int r = beg + wid; r < end; r += 4) {
        ushort4 h = *reinterpret_cast<const ushort4*>(ph + (size_t)r * D + lane * 4);
        ushort4 l = *reinterpret_cast<const ushort4*>(pl + (size_t)r * D + lane * 4);
        a0 += bf2f(h.x) + bf2f(l.x);
        a1 += bf2f(h.y) + bf2f(l.y);
        a2 += bf2f(h.z) + bf2f(l.z);
        a3 += bf2f(h.w) + bf2f(l.w);
    }
    red[wid][lane * 4 + 0] = a0;
    red[wid][lane * 4 + 1] = a1;
    red[wid][lane * 4 + 2] = a2;
    red[wid][lane * 4 + 3] = a3;
    __syncthreads();
    float s = red[0][t] + red[1][t] + red[2][t] + red[3][t];
    pooled[(size_t)g * D + t] = s;
}

// ---------------- MLP layer 1 (f32) ----------------
__global__ __launch_bounds__(256)
void mlp1_kernel(const float* __restrict__ pooled, const float* __restrict__ W1,
                 const float* __restrict__ b1, float* __restrict__ h) {
    __shared__ float p[D];
    int g = blockIdx.x, t = threadIdx.x;
    p[t] = pooled[(size_t)g * D + t];
    __syncthreads();
    float4 acc = make_float4(0.f, 0.f, 0.f, 0.f);
    for (int k = 0; k < D; ++k) {
        float4 w = *reinterpret_cast<const float4*>(W1 + (size_t)k * 1024 + t * 4);
        float pv = p[k];
        acc.x += pv * w.x; acc.y += pv * w.y; acc.z += pv * w.z; acc.w += pv * w.w;
    }
    float4 b = *reinterpret_cast<const float4*>(b1 + t * 4);
    acc.x = fmaxf(acc.x + b.x, 0.f);
    acc.y = fmaxf(acc.y + b.y, 0.f);
    acc.z = fmaxf(acc.z + b.z, 0.f);
    acc.w = fmaxf(acc.w + b.w, 0.f);
    *reinterpret_cast<float4*>(h + (size_t)g * 1024 + t * 4) = acc;
}

// ---------------- MLP layer 2 (f32) ----------------
__global__ __launch_bounds__(256)
void mlp2_kernel(const float* __restrict__ h, const float* __restrict__ W2,
                 const float* __restrict__ b2, float* __restrict__ out) {
    __shared__ float red[8][32];
    int g = blockIdx.x, t = threadIdx.x;
    int c = t & 31, kc = t >> 5;
    float s = 0.f;
    const float* hr = h + (size_t)g * 1024;
    for (int k = kc * 128; k < kc * 128 + 128; ++k)
        s += hr[k] * W2[(size_t)k * 32 + c];
    red[kc][c] = s;
    __syncthreads();
    if (t < 32) {
        float v = b2[t];
#pragma unroll
        for (int i = 0; i < 8; ++i) v += red[i][t];
        out[(size_t)g * 32 + t] = 1.f / (1.f + expf(-v));
    }
}

extern "C" void kernel_launch(void* const* d_in, const int* in_sizes, int n_in,
                              void* d_out, int out_size, void* d_ws, size_t ws_size,
                              hipStream_t stream) {
    const float* x      = (const float*)d_in[0];
    const int*   ei     = (const int*)d_in[1];
    const int*   batch  = (const int*)d_in[2];
    const float* W_rel  = (const float*)d_in[3];
    const float* W_root = (const float*)d_in[4];
    const float* b_conv = (const float*)d_in[5];
    const float* W1     = (const float*)d_in[6];
    const float* b1     = (const float*)d_in[7];
    const float* W2     = (const float*)d_in[8];
    const float* b2     = (const float*)d_in[9];
    float* outp = (float*)d_out;

    const size_t NF = (size_t)MPAD * D;
    // activation plane pairs: P0 (xh/xl), P1 (yh/yl), G (gh/gl)
    ushort* xh = (ushort*)d_ws;
    ushort* xl = xh + NF;
    ushort* yh = xl + NF;
    ushort* yl = yh + NF;
    ushort* gh = yl + NF;
    ushort* gl = gh + NF;
    ushort* Wh = gl + NF;                    // 3*256*512 each
    ushort* Wl = Wh + (size_t)NLAYERS * D * K2;
    float* pooled = (float*)(Wl + (size_t)NLAYERS * D * K2);
    float* hbuf   = pooled + (size_t)NGRAPH * D;
    int* deg       = (int*)(hbuf + (size_t)NGRAPH * 1024);
    int* row_start = deg + NNODES;           // NNODES+1
    int* cursor    = row_start + NNODES + 1;
    int* e_src     = cursor + NNODES;        // NEDGES
    int* gstart    = e_src + NEDGES;         // NGRAPH+1
    int* bsum      = gstart + NGRAPH + 1;    // NSCB
    int* boff      = bsum + NSCB;            // NSCB

    const int* srcp = ei;
    const int* dstp = ei + NEDGES;

    // CSR build (reused by all layers)
    hipMemsetAsync(deg, 0, NNODES * sizeof(int), stream);
    hist_kernel<<<(NEDGES + 255) / 256, 256, 0, stream>>>(dstp, deg, NEDGES);
    scan_part_kernel<<<NSCB, SCB, 0, stream>>>(deg, bsum);
    scan_bsum_kernel<<<1, 256, 0, stream>>>(bsum, boff);
    scan_final_kernel<<<NSCB, SCB, 0, stream>>>(deg, boff, row_start, cursor);
    fill_kernel<<<(NEDGES + 255) / 256, 256, 0, stream>>>(srcp, dstp, cursor, e_src, NEDGES);
    gstart_kernel<<<3, 256, 0, stream>>>(batch, gstart);

    prep_w_kernel<<<(NLAYERS * D * K2 + 255) / 256, 256, 0, stream>>>(W_rel, W_root, Wh, Wl);
    cvt_x_kernel<<<(int)((NF / 8 + 255) / 256), 256, 0, stream>>>(x, xh, xl);

    int gatherBlocks = (NNODES + 3) / 4;
    dim3 ggrid(MPAD / GBM, D / GBN);

    const ushort* curh = xh; const ushort* curl = xl;
    ushort* nxth = yh;       ushort* nxtl = yl;
    for (int L = 0; L < NLAYERS; ++L) {
        gather_hl_kernel<<<gatherBlocks, 256, 0, stream>>>(curh, curl, row_start, e_src, gh, gl);
        gemm_hl_kernel<<<ggrid, 256, 0, stream>>>(gh, gl, curh, curl,
                                                  Wh + (size_t)L * D * K2,
                                                  Wl + (size_t)L * D * K2,
                                                  b_conv + (size_t)L * D,
                                                  nxth, nxtl);
        // swap P-pair roles
        const ushort* th = curh; const ushort* tl = curl;
        curh = nxth; curl = nxtl;
        nxth = (ushort*)th; nxtl = (ushort*)tl;
        if (L == 0) { nxth = xh; nxtl = xl; }   // after L0: cur=P1, next writes into P0
    }

    pool_seg_kernel<<<NGRAPH, 256, 0, stream>>>(curh, curl, gstart, pooled);
    mlp1_kernel<<<NGRAPH, 256, 0, stream>>>(pooled, W1, b1, hbuf);
    mlp2_kernel<<<NGRAPH, 256, 0, stream>>>(hbuf, W2, b2, outp);
}